// Round 10
// baseline (296.021 us; speedup 1.0000x reference)
//
#include <hip/hip_runtime.h>
#include <math.h>

#define T_LEN 4096
#define B_SZ  512
#define CH    128          // chunk length (steps per phase)
#define NCH   32           // chunks = T_LEN / CH
#define PITCH 129          // pnib row pitch (bank spread)
#define PHASES 34          // NCH + 2 pipeline stages

typedef unsigned uv2 __attribute__((ext_vector_type(2)));

// emission: fl(fl(fl(-0.5*x)*x) - fl32(0.5*log(2*pi)))
__device__ __forceinline__ float emis(float xv) {
    float a = __fmul_rn(-0.5f, xv);
    float b = __fmul_rn(a, xv);
    return __fsub_rn(b, (float)0.9189385332046727);
}

// ---------------------------------------------------------------------------
#define DPP_ROR0(K, SRC) __builtin_amdgcn_update_dpp(0, (SRC), 0x120 + (K), 0xF, 0xF, false)
#define M3(x, y, z) fmaxf(fmaxf(x, y), z)

// Alternating-parity split-source chain (R10). Lane (j=tid&15, g=(tid>>4)&1,
// h=tid>>5); permlane32_swap pairs (j,g,h=0) <-> (j,g,h=1) (lane i^32).
//
// Step A: ALL lanes hold unrotated d[j]. h=0 computes dst j (sources via
//   ror:k, table aA0=A[sig_k(j)][j]); h=1 computes dst (j+8) (table
//   aA1=A[sig_k(j)][j+8]). Merge: rot=ror8(own) (rot-by-8 is self-inverse ->
//   direction-free), swap(rot), cross=(r0==rot)?r1:r0 (exact partner under
//   ANY swap semantics consistent with R8's pass: the non-cross slot always
//   VALUE-equals rot), m=max(own,cross). (j,0)->m_j, (j,1)->m_{j+8}: output
//   is h=1-rotated with zero extra ops.
// Step B: input h=1 rotated = R8's PROVEN form. own with table aB (aB1 =
//   A[sig_k(j)+8][j] via DPP-on-jh), merge swap(own)+max3(r0,r1,own) ->
//   m_j in BOTH halves -> output all-unrotated. No regen tail.
// Tables built with the SAME update_dpp sigma the asm ror:k uses ->
// pairing exact by construction, coverage verified under both directions.
#define ADPX(DST, K, TBL)                                                             \
    asm("v_add_f32_dpp %0, %1, %2 row_ror:" #K " row_mask:0xf bank_mask:0xf"          \
        : "=v"(DST) : "v"(dr), "v"(TBL[K]))

#define OWN8(TBL)                                                                     \
        float s0 = __fadd_rn(dr, TBL[0]);                                             \
        float s1, s2, s3, s4, s5, s6, s7;                                             \
        ADPX(s1, 1, TBL); ADPX(s2, 2, TBL); ADPX(s3, 3, TBL); ADPX(s4, 4, TBL);       \
        ADPX(s5, 5, TBL); ADPX(s6, 6, TBL); ADPX(s7, 7, TBL);                         \
        float u0 = M3(s0, s1, s2), u1 = M3(s3, s4, s5), u2 = fmaxf(s6, s7);           \
        float own = M3(u0, u1, u2);

#define STEPC_A(ET)                                                                   \
    {                                                                                 \
        OWN8(aA)                                                                      \
        float rot = __int_as_float(__builtin_amdgcn_update_dpp(                       \
            0, __float_as_int(own), 0x128, 0xF, 0xF, false));                         \
        unsigned rb = __float_as_uint(rot);                                           \
        uv2 rr = __builtin_amdgcn_permlane32_swap(rb, rb, false, false);              \
        float r0 = __uint_as_float(rr[0]), r1 = __uint_as_float(rr[1]);               \
        float cross = (r0 == rot) ? r1 : r0;  /* exact partner, semantics-safe */     \
        float m = fmaxf(own, cross);                                                  \
        dr = __fadd_rn(m, ET);                                                        \
    }

#define STEPC_B(ET)                                                                   \
    {                                                                                 \
        OWN8(aB)                                                                      \
        unsigned ob = __float_as_uint(own);                                           \
        uv2 rr = __builtin_amdgcn_permlane32_swap(ob, ob, false, false);              \
        float m = M3(__uint_as_float(rr[0]), __uint_as_float(rr[1]), own);            \
        dr = __fadd_rn(m, ET);                                                        \
    }

#define GRP4(QV, SLOTDW)                                                              \
    {                                                                                 \
        float4 dq;                                                                    \
        STEPC_A(QV.x) dq.x = dr; STEPC_B(QV.y) dq.y = dr;                             \
        STEPC_A(QV.z) dq.z = dr; STEPC_B(QV.w) dq.w = dr;                             \
        if (lo32) *(float4*)(db + (SLOTDW)) = dq;                                     \
    }

// Byte map application via v_perm — used for boundary chain.
#define PERMSEL(V, Q)                                                                 \
    {                                                                                 \
        int sel_ = (V) & 7;                                                           \
        int lo_, hi_;                                                                 \
        asm("v_perm_b32 %0, %1, %2, %3" : "=v"(lo_) : "v"((Q).y), "v"((Q).x), "v"(sel_)); \
        asm("v_perm_b32 %0, %1, %2, %3" : "=v"(hi_) : "v"((Q).w), "v"((Q).z), "v"(sel_)); \
        V = (((V) & 8) ? hi_ : lo_) & 0xff;                                           \
    }

// Generic byte map-walk: rows START..0, 8-row preload pipeline.
#define WALKN(BASE, CUR, PRE, POST, START)                                            \
    {                                                                                 \
        uint4 m_[8];                                                                  \
        _Pragma("unroll") for (int z_ = 0; z_ < 8; ++z_)                              \
            m_[z_] = *(const uint4*)((BASE) + ((START) - z_) * 16);                   \
        for (int r_ = (START); r_ >= 15; r_ -= 8) {                                   \
            uint4 n_[8];                                                              \
            _Pragma("unroll") for (int z_ = 0; z_ < 8; ++z_)                          \
                n_[z_] = *(const uint4*)((BASE) + (r_ - 8 - z_) * 16);                \
            _Pragma("unroll") for (int z_ = 0; z_ < 8; ++z_) {                        \
                PRE(r_ - z_, CUR) PERMSEL(CUR, m_[z_]) POST(r_ - z_, CUR)             \
            }                                                                         \
            _Pragma("unroll") for (int z_ = 0; z_ < 8; ++z_) m_[z_] = n_[z_];         \
        }                                                                             \
        _Pragma("unroll") for (int z_ = 0; z_ < 8; ++z_) {                            \
            PRE(7 - z_, CUR) PERMSEL(CUR, m_[z_]) POST(7 - z_, CUR)                   \
        }                                                                             \
    }

// Nibble-packed map application: row = u64 of 16 nibbles, next = (row>>4*cur)&15.
#define NIBHOP(V, Q) (V) = (int)(((Q) >> ((unsigned)(V) << 2)) & 15ull);

// Generic nibble map-walk: rows START..0, 8-row preload pipeline.
#define NWALKN(BASE, CUR, POST, START)                                                \
    {                                                                                 \
        const unsigned long long* bb_ = (BASE);                                       \
        unsigned long long m_[8];                                                     \
        _Pragma("unroll") for (int z_ = 0; z_ < 8; ++z_) m_[z_] = bb_[(START) - z_];  \
        for (int r_ = (START); r_ >= 15; r_ -= 8) {                                   \
            unsigned long long n_[8];                                                 \
            _Pragma("unroll") for (int z_ = 0; z_ < 8; ++z_) n_[z_] = bb_[r_ - 8 - z_]; \
            _Pragma("unroll") for (int z_ = 0; z_ < 8; ++z_) {                        \
                NIBHOP(CUR, m_[z_]) POST(r_ - z_, CUR)                                \
            }                                                                         \
            _Pragma("unroll") for (int z_ = 0; z_ < 8; ++z_) m_[z_] = n_[z_];         \
        }                                                                             \
        _Pragma("unroll") for (int z_ = 0; z_ < 8; ++z_) {                            \
            NIBHOP(CUR, m_[z_]) POST(7 - z_, CUR)                                     \
        }                                                                             \
    }

#define NOPX(r, c)
#define EBL_PRE(r, c) eb[r] = (unsigned char)(c);
#define OUT_POST(r, c) ob[r] = (c);

// psi column operand: wave-uniform scalar via v_readlane from a preloaded VGPR.
// Zero memory ops in the phase loop. All indices compile-time.
#define RLF(V, L) __int_as_float(__builtin_amdgcn_readlane(__float_as_int(V), (L)))

// Dual-row psi: one readlane per (jj,i), shared by rows A and B.
#define PSI2_I(I, V, BL)                                                              \
    {                                                                                 \
        float cs_ = RLF(V, (BL) + (I));                                               \
        float sA_ = __fadd_rn(ddA[I], cs_);                                           \
        if (sA_ > bestA) argA = I;  /* first-wins tie rule */                         \
        bestA = fmaxf(bestA, sA_);                                                    \
        float sB_ = __fadd_rn(ddB[I], cs_);                                           \
        if (sB_ > bestB) argB = I;                                                    \
        bestB = fmaxf(bestB, sB_);                                                    \
    }

#define PSI2_J(JJ, V)                                                                 \
    {                                                                                 \
        float c0_ = RLF(V, (((JJ) & 3) * 16) + 0);                                    \
        float bestA = __fadd_rn(ddA[0], c0_); int argA = 0;                           \
        float bestB = __fadd_rn(ddB[0], c0_); int argB = 0;                           \
        PSI2_I(1, V, ((JJ) & 3) * 16)  PSI2_I(2, V, ((JJ) & 3) * 16)                  \
        PSI2_I(3, V, ((JJ) & 3) * 16)  PSI2_I(4, V, ((JJ) & 3) * 16)                  \
        PSI2_I(5, V, ((JJ) & 3) * 16)  PSI2_I(6, V, ((JJ) & 3) * 16)                  \
        PSI2_I(7, V, ((JJ) & 3) * 16)  PSI2_I(8, V, ((JJ) & 3) * 16)                  \
        PSI2_I(9, V, ((JJ) & 3) * 16)  PSI2_I(10, V, ((JJ) & 3) * 16)                 \
        PSI2_I(11, V, ((JJ) & 3) * 16) PSI2_I(12, V, ((JJ) & 3) * 16)                 \
        PSI2_I(13, V, ((JJ) & 3) * 16) PSI2_I(14, V, ((JJ) & 3) * 16)                 \
        PSI2_I(15, V, ((JJ) & 3) * 16)                                                \
        pkA |= (unsigned long long)argA << ((JJ) * 4);                                \
        pkB |= (unsigned long long)argB << ((JJ) * 4);                                \
    }

// ---------------------------------------------------------------------------
// Single fused kernel, chunk = 128. 2 batches/block, 4 waves (one per SIMD).
// Prologue: logA/logAT into LDS (bit-exact fp64-log) + E chunks 0,1 into ring.
// Wave 0 (ALL 64 lanes): alternating-parity split-source Viterbi chains;
//         lanes 0-31 (h=0 rows) always hold the true deltas and store dbuf.
// Waves 1,2: psi of chunk p-1, 2 rows/lane -> nibble-packed pnib; logAT via
//            per-phase v_readlane from 4 preloaded VGPRs (asm-pinned in-loop).
// Wave 3: emissions for chunk p+2 into ring + nibble map-walk of chunk p-2.
// Tail: argmax + boundary chain (32 hops) + 64 chunk walks writing out.
__global__ __launch_bounds__(256) void k_fused(const float* __restrict__ x,
                                               const float* __restrict__ hmm,
                                               int* __restrict__ out) {
    __shared__ __align__(16) float dbuf[2][2][16][132];  // 33792 B (slot 128 = carry)
    __shared__ unsigned long long pnib[2][NCH * PITCH];  // 66048 B
    __shared__ uint4 Mlv[2][NCH];                        // 1024 B
    __shared__ unsigned char Ebl[2][NCH];                // 64 B
    __shared__ float carry_l[2][16];                     // 128 B
    __shared__ float logA_l[256];                        // 1024 B
    __shared__ float logAT_l[256];                       // 1024 B
    __shared__ __align__(16) float Ebuf[4][2][CH];       // 4096 B (4-deep ring)

    const int tid = threadIdx.x;
    const int wave = tid >> 6;
    const int blk = blockIdx.x;

    // ---- prologue: logA/logAT (bit-exact) + emission chunks 0,1 ----
    {
        const int pi = tid >> 4, pj = tid & 15;
        const float* row = hmm + pi * 16;
        float r8[8];
#pragma unroll
        for (int k = 0; k < 8; ++k) r8[k] = __fadd_rn(row[k], row[k + 8]);
        float s = __fadd_rn(
            __fadd_rn(__fadd_rn(r8[0], r8[1]), __fadd_rn(r8[2], r8[3])),
            __fadd_rn(__fadd_rn(r8[4], r8[5]), __fadd_rn(r8[6], r8[7])));
        float la = (float)log((double)row[pj]);
        float ls = (float)log((double)s);
        float v = __fsub_rn(la, ls);
        logA_l[tid] = v;
        logAT_l[pj * 16 + pi] = v;
        // E chunks 0,1: 512 values / 256 threads = 2 each (t <= 256, no bound check)
        const int cc0 = tid >> 7, gp = (tid >> 6) & 1, l0 = tid & 63;
        const size_t xb = (size_t)(blk * 2 + gp) * T_LEN + CH * cc0 + l0 + 1;
        Ebuf[cc0][gp][l0]      = emis(x[xb]);
        Ebuf[cc0][gp][l0 + 64] = emis(x[xb + 64]);
    }
    __syncthreads();

    if (wave == 0) {
        asm volatile("s_setprio 3");
        const int j = tid & 15;
        const int g = (tid >> 4) & 1;   // batch within block
        const int h = tid >> 5;         // source-half (swap partner: lane ^32)
        const bool lo32 = (tid < 32);   // h=0 rows: always true deltas
        const int jh = (j + 8 * h) & 15;
        float aA[8], aB[8];
        float dr;
        float4 q0, q1, q2, q3;
        {
            // Tables built with the SAME DPP sigma the step's ror:k uses.
            // aA[k] = A[sig_k(j)][jh]      (step A: unrotated input, dst jh)
            // aB[k] = A[sig_k(jh)... ][j]  (step B: rotated input, dst j)
            aA[0] = logA_l[j * 16 + jh];
            aB[0] = logA_l[jh * 16 + j];
#define LOADT(K) { int sA_ = DPP_ROR0(K, j);  aA[K] = logA_l[sA_ * 16 + jh];          \
                   int sB_ = DPP_ROR0(K, jh); aB[K] = logA_l[sB_ * 16 + j]; }
            LOADT(1) LOADT(2) LOADT(3) LOADT(4) LOADT(5) LOADT(6) LOADT(7)
#undef LOADT
            const int b = blk * 2 + g;
            float e0 = emis(x[(size_t)b * T_LEN]);
            dr = __fadd_rn(logA_l[j], e0);           // delta0, UNROTATED in all lanes
            const float4* e0p = (const float4*)&Ebuf[0][g][0];
            q0 = e0p[0]; q1 = e0p[1]; q2 = e0p[2]; q3 = e0p[3];
        }
        for (int p = 0; p < PHASES; ++p) {
            __syncthreads();
            if (p < NCH) {
                float* db = &dbuf[p & 1][g][j][0];
                if (lo32) db[128] = dr;               // delta at t = 128p (carry)
                const float4* ecur = (const float4*)&Ebuf[p & 3][g][0];
                const float4* enxt = (const float4*)&Ebuf[(p + 1) & 3][g][0];
                if (p < NCH - 1) {
#pragma clang loop unroll(disable)
                    for (int ii = 0; ii < 7; ++ii) {
                        GRP4(q0, ii * 16 + 0)  q0 = ecur[(ii + 1) * 4 + 0];
                        GRP4(q1, ii * 16 + 4)  q1 = ecur[(ii + 1) * 4 + 1];
                        GRP4(q2, ii * 16 + 8)  q2 = ecur[(ii + 1) * 4 + 2];
                        GRP4(q3, ii * 16 + 12) q3 = ecur[(ii + 1) * 4 + 3];
                    }
                    // last quad-group of this chunk; prefetch chunk p+1
                    // (filled by wave 3 during phase p-1 -> barrier-ordered)
                    GRP4(q0, 112) q0 = enxt[0];
                    GRP4(q1, 116) q1 = enxt[1];
                    GRP4(q2, 120) q2 = enxt[2];
                    GRP4(q3, 124) q3 = enxt[3];
                } else {
#pragma clang loop unroll(disable)
                    for (int ii = 0; ii < 7; ++ii) {
                        GRP4(q0, ii * 16 + 0)  q0 = ecur[(ii + 1) * 4 + 0];
                        GRP4(q1, ii * 16 + 4)  q1 = ecur[(ii + 1) * 4 + 1];
                        GRP4(q2, ii * 16 + 8)  q2 = ecur[(ii + 1) * 4 + 2];
                        GRP4(q3, ii * 16 + 12) q3 = ecur[(ii + 1) * 4 + 3];
                    }
                    GRP4(q0, 112) GRP4(q1, 116) GRP4(q2, 120)    // t=4081..4092
                    STEPC_A(q3.x) if (lo32) db[124] = dr;         // t=4093 (offs 124, A)
                    STEPC_B(q3.y) if (lo32) db[125] = dr;         // t=4094 (B)
                    STEPC_A(q3.z) if (lo32) db[126] = dr;         // t=4095 (A)
                }
            }
        }
        if (lo32) carry_l[g][j] = dr;
    } else if (wave <= 2) {
        const int g2 = wave - 1;
        const int r = tid & 63;
        // preload logAT into 4 VGPRs/lane: vqN holds logAT_l[N*64 + lane]
        float vq0 = logAT_l[r];
        float vq1 = logAT_l[64 + r];
        float vq2 = logAT_l[128 + r];
        float vq3 = logAT_l[192 + r];
        for (int p = 0; p < PHASES; ++p) {
            __syncthreads();
            const int c = p - 1;
            if (c >= 0 && c < NCH) {
                const int q = c & 1;
                const int rsA = (r == 0) ? 128 : (r - 1);
                const int rsB = r + 63;
                float ddA[16], ddB[16];
#pragma unroll
                for (int i = 0; i < 16; ++i) {
                    ddA[i] = dbuf[q][g2][i][rsA];
                    ddB[i] = dbuf[q][g2][i][rsB];
                }
                // pin vq* as loop-variant: blocks hoisting of the readlanes
                asm volatile("" : "+v"(vq0), "+v"(vq1), "+v"(vq2), "+v"(vq3));
                unsigned long long pkA = 0ull, pkB = 0ull;
                PSI2_J(0, vq0)  PSI2_J(1, vq0)  PSI2_J(2, vq0)  PSI2_J(3, vq0)
                PSI2_J(4, vq1)  PSI2_J(5, vq1)  PSI2_J(6, vq1)  PSI2_J(7, vq1)
                PSI2_J(8, vq2)  PSI2_J(9, vq2)  PSI2_J(10, vq2) PSI2_J(11, vq2)
                PSI2_J(12, vq3) PSI2_J(13, vq3) PSI2_J(14, vq3) PSI2_J(15, vq3)
                // c==NCH-1, rowB==127: t=4096 absent -> identity map
                if (c == NCH - 1 && r == 63) pkB = 0xFEDCBA9876543210ull;
                pnib[g2][c * PITCH + r]      = pkA;
                pnib[g2][c * PITCH + r + 64] = pkB;
            }
        }
    } else {
        const int l = tid - 192;
        const int g3 = l >> 4, z = l & 15;
        for (int p = 0; p < PHASES; ++p) {
            __syncthreads();
            // emissions for chunk p+2 into the ring (2 chunks ahead of wave 0's
            // main reads; 1 ahead of its end-of-chunk prefetch -> race-free)
            const int cc = p + 2;
            if (cc < NCH) {
                const int t1 = CH * cc + l + 1;
                const int t2 = t1 + 64;
                Ebuf[cc & 3][0][l] = emis(x[(size_t)(blk * 2 + 0) * T_LEN + t1]);
                Ebuf[cc & 3][1][l] = emis(x[(size_t)(blk * 2 + 1) * T_LEN + t1]);
                if (t2 <= T_LEN - 1) {
                    Ebuf[cc & 3][0][l + 64] = emis(x[(size_t)(blk * 2 + 0) * T_LEN + t2]);
                    Ebuf[cc & 3][1][l + 64] = emis(x[(size_t)(blk * 2 + 1) * T_LEN + t2]);
                }
            }
            const int c = p - 2;
            if (c >= 0 && l < 32) {
                int cur = z;
                NWALKN(&pnib[g3][c * PITCH], cur, NOPX, 127)
                ((unsigned char*)&Mlv[g3][c])[z] = (unsigned char)cur;
            }
        }
    }

    // ---- fused backtrace tail (all LDS-resident) ----
    __syncthreads();
    if (tid < 2) {
        const int g = tid;
        float best = carry_l[g][0]; int zT = 0;
#pragma unroll
        for (int i = 1; i < 16; ++i) {
            float s = carry_l[g][i];
            if (s > best) zT = i;
            best = fmaxf(best, s);
        }
        int z = zT;
        unsigned char* eb = &Ebl[g][0];
        WALKN((const unsigned char*)&Mlv[g][0], z, EBL_PRE, NOPX, NCH - 1)
    }
    __syncthreads();
    if (tid < 64) {
        const int g = tid >> 5, c = tid & 31;
        int* ob = out + (size_t)(blk * 2 + g) * T_LEN + c * CH;
        int cur = Ebl[g][c];
        NWALKN(&pnib[g][c * PITCH], cur, OUT_POST, 127)  // last-chunk identity hop writes out[4095]=zT
    }
}

// ---------------------------------------------------------------------------
extern "C" void kernel_launch(void* const* d_in, const int* in_sizes, int n_in,
                              void* d_out, int out_size, void* d_ws, size_t ws_size,
                              hipStream_t stream) {
    (void)in_sizes; (void)n_in; (void)out_size; (void)d_ws; (void)ws_size;
    const float* x   = (const float*)d_in[0];   // [512][4096] fp32
    const float* hmm = (const float*)d_in[1];   // [64][16][16] fp32 (only [0] used)
    int* out = (int*)d_out;                     // [512][4096] int32

    hipLaunchKernelGGL(k_fused, dim3(B_SZ / 2), dim3(256), 0, stream, x, hmm, out);
}

// Round 11
// 289.071 us; speedup vs baseline: 1.0240x; 1.0240x over previous
//
#include <hip/hip_runtime.h>
#include <math.h>

#define T_LEN 4096
#define B_SZ  512
#define CH    128          // chunk length (steps per phase)
#define NCH   32           // chunks = T_LEN / CH
#define PITCH 129          // pnib row pitch (bank spread)
#define PHASES 34          // NCH + 2 pipeline stages

// emission: fl(fl(fl(-0.5*x)*x) - fl32(0.5*log(2*pi)))
__device__ __forceinline__ float emis(float xv) {
    float a = __fmul_rn(-0.5f, xv);
    float b = __fmul_rn(a, xv);
    return __fsub_rn(b, (float)0.9189385332046727);
}

// ---------------------------------------------------------------------------
#define DPP_ROR0(K, SRC) __builtin_amdgcn_update_dpp(0, (SRC), 0x120 + (K), 0xF, 0xF, false)
#define M3(x, y, z) fmaxf(fmaxf(x, y), z)

// R4-proven chain step: 16 lanes/batch, d holds delta[j]. 1 plain add + 15
// DPP row_ror adds (a[] table built with the SAME DPP sigma -> pairing exact
// by construction), depth-optimal max3 tree (16->6->2->1), add E.
// Dependency levels/step: addE(1) + dpp-add(1) + tree(3) = 5 — measured
// session floor (R5-R10: fewer instructions via permlane split-source gave
// MORE levels and ran equal-or-slower; chain is dep-latency-bound, ~12ns/level).
#define ADDPP(DST, K)                                                                 \
    asm("v_add_f32_dpp %0, %1, %2 row_ror:" #K " row_mask:0xf bank_mask:0xf"          \
        : "=v"(DST) : "v"(d), "v"(a[K]))

#define STEPC(ET)                                                                     \
    {                                                                                 \
        float s0 = __fadd_rn(d, a[0]);                                                \
        float s1, s2, s3, s4, s5, s6, s7, s8, s9, s10, s11, s12, s13, s14, s15;       \
        ADDPP(s1, 1);   ADDPP(s2, 2);   ADDPP(s3, 3);   ADDPP(s4, 4);                 \
        ADDPP(s5, 5);   ADDPP(s6, 6);   ADDPP(s7, 7);   ADDPP(s8, 8);                 \
        ADDPP(s9, 9);   ADDPP(s10, 10); ADDPP(s11, 11); ADDPP(s12, 12);               \
        ADDPP(s13, 13); ADDPP(s14, 14); ADDPP(s15, 15);                               \
        float u0 = M3(s0, s1, s2),  u1 = M3(s3, s4, s5),  u2 = M3(s6, s7, s8);        \
        float u3 = M3(s9, s10, s11), u4 = M3(s12, s13, s14);                          \
        float m = fmaxf(M3(u0, u1, u2), M3(u3, u4, s15));                             \
        d = __fadd_rn(m, ET);                                                         \
    }

#define GRP4(QV, SLOTDW)                                                              \
    {                                                                                 \
        float4 dq;                                                                    \
        STEPC(QV.x) dq.x = d; STEPC(QV.y) dq.y = d;                                   \
        STEPC(QV.z) dq.z = d; STEPC(QV.w) dq.w = d;                                   \
        *(float4*)(db + (SLOTDW)) = dq;                                               \
    }

// Byte map application via v_perm — used for boundary chain.
#define PERMSEL(V, Q)                                                                 \
    {                                                                                 \
        int sel_ = (V) & 7;                                                           \
        int lo_, hi_;                                                                 \
        asm("v_perm_b32 %0, %1, %2, %3" : "=v"(lo_) : "v"((Q).y), "v"((Q).x), "v"(sel_)); \
        asm("v_perm_b32 %0, %1, %2, %3" : "=v"(hi_) : "v"((Q).w), "v"((Q).z), "v"(sel_)); \
        V = (((V) & 8) ? hi_ : lo_) & 0xff;                                           \
    }

// Generic byte map-walk: rows START..0, 8-row preload pipeline.
#define WALKN(BASE, CUR, PRE, POST, START)                                            \
    {                                                                                 \
        uint4 m_[8];                                                                  \
        _Pragma("unroll") for (int z_ = 0; z_ < 8; ++z_)                              \
            m_[z_] = *(const uint4*)((BASE) + ((START) - z_) * 16);                   \
        for (int r_ = (START); r_ >= 15; r_ -= 8) {                                   \
            uint4 n_[8];                                                              \
            _Pragma("unroll") for (int z_ = 0; z_ < 8; ++z_)                          \
                n_[z_] = *(const uint4*)((BASE) + (r_ - 8 - z_) * 16);                \
            _Pragma("unroll") for (int z_ = 0; z_ < 8; ++z_) {                        \
                PRE(r_ - z_, CUR) PERMSEL(CUR, m_[z_]) POST(r_ - z_, CUR)             \
            }                                                                         \
            _Pragma("unroll") for (int z_ = 0; z_ < 8; ++z_) m_[z_] = n_[z_];         \
        }                                                                             \
        _Pragma("unroll") for (int z_ = 0; z_ < 8; ++z_) {                            \
            PRE(7 - z_, CUR) PERMSEL(CUR, m_[z_]) POST(7 - z_, CUR)                   \
        }                                                                             \
    }

// Nibble-packed map application: row = u64 of 16 nibbles, next = (row>>4*cur)&15.
#define NIBHOP(V, Q) (V) = (int)(((Q) >> ((unsigned)(V) << 2)) & 15ull);

// Generic nibble map-walk: rows START..0, 8-row preload pipeline.
#define NWALKN(BASE, CUR, POST, START)                                                \
    {                                                                                 \
        const unsigned long long* bb_ = (BASE);                                       \
        unsigned long long m_[8];                                                     \
        _Pragma("unroll") for (int z_ = 0; z_ < 8; ++z_) m_[z_] = bb_[(START) - z_];  \
        for (int r_ = (START); r_ >= 15; r_ -= 8) {                                   \
            unsigned long long n_[8];                                                 \
            _Pragma("unroll") for (int z_ = 0; z_ < 8; ++z_) n_[z_] = bb_[r_ - 8 - z_]; \
            _Pragma("unroll") for (int z_ = 0; z_ < 8; ++z_) {                        \
                NIBHOP(CUR, m_[z_]) POST(r_ - z_, CUR)                                \
            }                                                                         \
            _Pragma("unroll") for (int z_ = 0; z_ < 8; ++z_) m_[z_] = n_[z_];         \
        }                                                                             \
        _Pragma("unroll") for (int z_ = 0; z_ < 8; ++z_) {                            \
            NIBHOP(CUR, m_[z_]) POST(7 - z_, CUR)                                     \
        }                                                                             \
    }

#define NOPX(r, c)
#define EBL_PRE(r, c) eb[r] = (unsigned char)(c);
#define OUT_POST(r, c) ob[r] = (c);

// psi column operand: wave-uniform scalar via v_readlane from a preloaded VGPR.
// Zero memory ops in the phase loop. All indices compile-time.
#define RLF(V, L) __int_as_float(__builtin_amdgcn_readlane(__float_as_int(V), (L)))

// Dual-row psi: one readlane per (jj,i), shared by rows A and B.
#define PSI2_I(I, V, BL)                                                              \
    {                                                                                 \
        float cs_ = RLF(V, (BL) + (I));                                               \
        float sA_ = __fadd_rn(ddA[I], cs_);                                           \
        if (sA_ > bestA) argA = I;  /* first-wins tie rule */                         \
        bestA = fmaxf(bestA, sA_);                                                    \
        float sB_ = __fadd_rn(ddB[I], cs_);                                           \
        if (sB_ > bestB) argB = I;                                                    \
        bestB = fmaxf(bestB, sB_);                                                    \
    }

#define PSI2_J(JJ, V)                                                                 \
    {                                                                                 \
        float c0_ = RLF(V, (((JJ) & 3) * 16) + 0);                                    \
        float bestA = __fadd_rn(ddA[0], c0_); int argA = 0;                           \
        float bestB = __fadd_rn(ddB[0], c0_); int argB = 0;                           \
        PSI2_I(1, V, ((JJ) & 3) * 16)  PSI2_I(2, V, ((JJ) & 3) * 16)                  \
        PSI2_I(3, V, ((JJ) & 3) * 16)  PSI2_I(4, V, ((JJ) & 3) * 16)                  \
        PSI2_I(5, V, ((JJ) & 3) * 16)  PSI2_I(6, V, ((JJ) & 3) * 16)                  \
        PSI2_I(7, V, ((JJ) & 3) * 16)  PSI2_I(8, V, ((JJ) & 3) * 16)                  \
        PSI2_I(9, V, ((JJ) & 3) * 16)  PSI2_I(10, V, ((JJ) & 3) * 16)                 \
        PSI2_I(11, V, ((JJ) & 3) * 16) PSI2_I(12, V, ((JJ) & 3) * 16)                 \
        PSI2_I(13, V, ((JJ) & 3) * 16) PSI2_I(14, V, ((JJ) & 3) * 16)                 \
        PSI2_I(15, V, ((JJ) & 3) * 16)                                                \
        pkA |= (unsigned long long)argA << ((JJ) * 4);                                \
        pkB |= (unsigned long long)argB << ((JJ) * 4);                                \
    }

// ---------------------------------------------------------------------------
// Single fused kernel, chunk = 128 (R4 configuration — session best).
// 2 batches/block, 4 waves (one per SIMD).
// Prologue: logA/logAT into LDS (bit-exact fp64-log) + E chunks 0,1 into ring.
// Wave 0 (g<2, lanes 0-31): R4 Viterbi chains; E from LDS ring, delta->dbuf.
// Waves 1,2: psi of chunk p-1, 2 rows/lane -> nibble-packed pnib; logAT via
//            per-phase v_readlane from 4 preloaded VGPRs (asm-pinned in-loop).
// Wave 3: emissions for chunk p+2 into ring + nibble map-walk of chunk p-2.
// Tail: argmax + boundary chain (32 hops) + 64 chunk walks writing out.
__global__ __launch_bounds__(256) void k_fused(const float* __restrict__ x,
                                               const float* __restrict__ hmm,
                                               int* __restrict__ out) {
    __shared__ __align__(16) float dbuf[2][2][16][132];  // 33792 B (slot 128 = carry)
    __shared__ unsigned long long pnib[2][NCH * PITCH];  // 66048 B
    __shared__ uint4 Mlv[2][NCH];                        // 1024 B
    __shared__ unsigned char Ebl[2][NCH];                // 64 B
    __shared__ float carry_l[2][16];                     // 128 B
    __shared__ float logA_l[256];                        // 1024 B
    __shared__ float logAT_l[256];                       // 1024 B
    __shared__ __align__(16) float Ebuf[4][2][CH];       // 4096 B (4-deep ring)

    const int tid = threadIdx.x;
    const int wave = tid >> 6;
    const int blk = blockIdx.x;

    // ---- prologue: logA/logAT (bit-exact) + emission chunks 0,1 ----
    {
        const int pi = tid >> 4, pj = tid & 15;
        const float* row = hmm + pi * 16;
        float r8[8];
#pragma unroll
        for (int k = 0; k < 8; ++k) r8[k] = __fadd_rn(row[k], row[k + 8]);
        float s = __fadd_rn(
            __fadd_rn(__fadd_rn(r8[0], r8[1]), __fadd_rn(r8[2], r8[3])),
            __fadd_rn(__fadd_rn(r8[4], r8[5]), __fadd_rn(r8[6], r8[7])));
        float la = (float)log((double)row[pj]);
        float ls = (float)log((double)s);
        float v = __fsub_rn(la, ls);
        logA_l[tid] = v;
        logAT_l[pj * 16 + pi] = v;
        // E chunks 0,1: 512 values / 256 threads = 2 each (t <= 256, no bound check)
        const int cc0 = tid >> 7, gp = (tid >> 6) & 1, l0 = tid & 63;
        const size_t xb = (size_t)(blk * 2 + gp) * T_LEN + CH * cc0 + l0 + 1;
        Ebuf[cc0][gp][l0]      = emis(x[xb]);
        Ebuf[cc0][gp][l0 + 64] = emis(x[xb + 64]);
    }
    __syncthreads();

    if (wave == 0) {
        asm volatile("s_setprio 3");
        const int j = tid & 15, g = tid >> 4;  // active g<2
        float a[16];
        float d = 0.f;
        float4 q0, q1, q2, q3;
        if (g < 2) {
            a[0] = logA_l[j * 16 + j];
#define LOADA(K) { int sk = DPP_ROR0(K, j); a[K] = logA_l[sk * 16 + j]; }
            LOADA(1)  LOADA(2)  LOADA(3)  LOADA(4)  LOADA(5)
            LOADA(6)  LOADA(7)  LOADA(8)  LOADA(9)  LOADA(10)
            LOADA(11) LOADA(12) LOADA(13) LOADA(14) LOADA(15)
#undef LOADA
            const int b = blk * 2 + g;
            float e0 = emis(x[(size_t)b * T_LEN]);
            d = __fadd_rn(logA_l[j], e0);            // delta0
            const float4* e0p = (const float4*)&Ebuf[0][g][0];
            q0 = e0p[0]; q1 = e0p[1]; q2 = e0p[2]; q3 = e0p[3];
        }
        for (int p = 0; p < PHASES; ++p) {
            __syncthreads();
            if (p < NCH && g < 2) {
                float* db = &dbuf[p & 1][g][j][0];
                db[128] = d;                          // delta at t = 128p (carry)
                const float4* ecur = (const float4*)&Ebuf[p & 3][g][0];
                const float4* enxt = (const float4*)&Ebuf[(p + 1) & 3][g][0];
                if (p < NCH - 1) {
#pragma clang loop unroll(disable)
                    for (int ii = 0; ii < 7; ++ii) {
                        GRP4(q0, ii * 16 + 0)  q0 = ecur[(ii + 1) * 4 + 0];
                        GRP4(q1, ii * 16 + 4)  q1 = ecur[(ii + 1) * 4 + 1];
                        GRP4(q2, ii * 16 + 8)  q2 = ecur[(ii + 1) * 4 + 2];
                        GRP4(q3, ii * 16 + 12) q3 = ecur[(ii + 1) * 4 + 3];
                    }
                    // last quad-group of this chunk; prefetch chunk p+1
                    // (filled by wave 3 during phase p-1 -> barrier-ordered)
                    GRP4(q0, 112) q0 = enxt[0];
                    GRP4(q1, 116) q1 = enxt[1];
                    GRP4(q2, 120) q2 = enxt[2];
                    GRP4(q3, 124) q3 = enxt[3];
                } else {
#pragma clang loop unroll(disable)
                    for (int ii = 0; ii < 7; ++ii) {
                        GRP4(q0, ii * 16 + 0)  q0 = ecur[(ii + 1) * 4 + 0];
                        GRP4(q1, ii * 16 + 4)  q1 = ecur[(ii + 1) * 4 + 1];
                        GRP4(q2, ii * 16 + 8)  q2 = ecur[(ii + 1) * 4 + 2];
                        GRP4(q3, ii * 16 + 12) q3 = ecur[(ii + 1) * 4 + 3];
                    }
                    GRP4(q0, 112) GRP4(q1, 116) GRP4(q2, 120)    // t=4081..4092
                    STEPC(q3.x) db[124] = d;                      // t=4093
                    STEPC(q3.y) db[125] = d;                      // t=4094
                    STEPC(q3.z) db[126] = d;                      // t=4095
                }
            }
        }
        if (g < 2) carry_l[g][j] = d;
    } else if (wave <= 2) {
        const int g2 = wave - 1;
        const int r = tid & 63;
        // preload logAT into 4 VGPRs/lane: vqN holds logAT_l[N*64 + lane]
        float vq0 = logAT_l[r];
        float vq1 = logAT_l[64 + r];
        float vq2 = logAT_l[128 + r];
        float vq3 = logAT_l[192 + r];
        for (int p = 0; p < PHASES; ++p) {
            __syncthreads();
            const int c = p - 1;
            if (c >= 0 && c < NCH) {
                const int q = c & 1;
                const int rsA = (r == 0) ? 128 : (r - 1);
                const int rsB = r + 63;
                float ddA[16], ddB[16];
#pragma unroll
                for (int i = 0; i < 16; ++i) {
                    ddA[i] = dbuf[q][g2][i][rsA];
                    ddB[i] = dbuf[q][g2][i][rsB];
                }
                // pin vq* as loop-variant: blocks hoisting of the readlanes
                asm volatile("" : "+v"(vq0), "+v"(vq1), "+v"(vq2), "+v"(vq3));
                unsigned long long pkA = 0ull, pkB = 0ull;
                PSI2_J(0, vq0)  PSI2_J(1, vq0)  PSI2_J(2, vq0)  PSI2_J(3, vq0)
                PSI2_J(4, vq1)  PSI2_J(5, vq1)  PSI2_J(6, vq1)  PSI2_J(7, vq1)
                PSI2_J(8, vq2)  PSI2_J(9, vq2)  PSI2_J(10, vq2) PSI2_J(11, vq2)
                PSI2_J(12, vq3) PSI2_J(13, vq3) PSI2_J(14, vq3) PSI2_J(15, vq3)
                // c==NCH-1, rowB==127: t=4096 absent -> identity map
                if (c == NCH - 1 && r == 63) pkB = 0xFEDCBA9876543210ull;
                pnib[g2][c * PITCH + r]      = pkA;
                pnib[g2][c * PITCH + r + 64] = pkB;
            }
        }
    } else {
        const int l = tid - 192;
        const int g3 = l >> 4, z = l & 15;
        for (int p = 0; p < PHASES; ++p) {
            __syncthreads();
            // emissions for chunk p+2 into the ring (2 chunks ahead of wave 0's
            // main reads; 1 ahead of its end-of-chunk prefetch -> race-free)
            const int cc = p + 2;
            if (cc < NCH) {
                const int t1 = CH * cc + l + 1;
                const int t2 = t1 + 64;
                Ebuf[cc & 3][0][l] = emis(x[(size_t)(blk * 2 + 0) * T_LEN + t1]);
                Ebuf[cc & 3][1][l] = emis(x[(size_t)(blk * 2 + 1) * T_LEN + t1]);
                if (t2 <= T_LEN - 1) {
                    Ebuf[cc & 3][0][l + 64] = emis(x[(size_t)(blk * 2 + 0) * T_LEN + t2]);
                    Ebuf[cc & 3][1][l + 64] = emis(x[(size_t)(blk * 2 + 1) * T_LEN + t2]);
                }
            }
            const int c = p - 2;
            if (c >= 0 && l < 32) {
                int cur = z;
                NWALKN(&pnib[g3][c * PITCH], cur, NOPX, 127)
                ((unsigned char*)&Mlv[g3][c])[z] = (unsigned char)cur;
            }
        }
    }

    // ---- fused backtrace tail (all LDS-resident) ----
    __syncthreads();
    if (tid < 2) {
        const int g = tid;
        float best = carry_l[g][0]; int zT = 0;
#pragma unroll
        for (int i = 1; i < 16; ++i) {
            float s = carry_l[g][i];
            if (s > best) zT = i;
            best = fmaxf(best, s);
        }
        int z = zT;
        unsigned char* eb = &Ebl[g][0];
        WALKN((const unsigned char*)&Mlv[g][0], z, EBL_PRE, NOPX, NCH - 1)
    }
    __syncthreads();
    if (tid < 64) {
        const int g = tid >> 5, c = tid & 31;
        int* ob = out + (size_t)(blk * 2 + g) * T_LEN + c * CH;
        int cur = Ebl[g][c];
        NWALKN(&pnib[g][c * PITCH], cur, OUT_POST, 127)  // last-chunk identity hop writes out[4095]=zT
    }
}

// ---------------------------------------------------------------------------
extern "C" void kernel_launch(void* const* d_in, const int* in_sizes, int n_in,
                              void* d_out, int out_size, void* d_ws, size_t ws_size,
                              hipStream_t stream) {
    (void)in_sizes; (void)n_in; (void)out_size; (void)d_ws; (void)ws_size;
    const float* x   = (const float*)d_in[0];   // [512][4096] fp32
    const float* hmm = (const float*)d_in[1];   // [64][16][16] fp32 (only [0] used)
    int* out = (int*)d_out;                     // [512][4096] int32

    hipLaunchKernelGGL(k_fused, dim3(B_SZ / 2), dim3(256), 0, stream, x, hmm, out);
}